// Round 1
// baseline (1553.735 us; speedup 1.0000x reference)
//
#include <hip/hip_runtime.h>
#include <math.h>

#define B_ 64
#define T_ 256
#define F_ 64
#define H_ 64
#define NROW (B_ * F_) /* 4096 */

__device__ __forceinline__ float bcastf(float v, int k) {
  return __int_as_float(__builtin_amdgcn_readlane(__float_as_int(v), k));
}

__device__ __forceinline__ float sigm(float x) {
  return 1.0f / (1.0f + __expf(-x));
}

__device__ __forceinline__ float tanh_f(float x) {
  float ax = fabsf(x);
  float e = __expf(-2.0f * ax);
  float r = (1.0f - e) / (1.0f + e);
  return copysignf(r, x);
}

// One wave per (direction, row). Lane j owns GRU unit j.
// w_hh rows {j, 64+j, 128+j} live in VGPRs (192 regs). h[k] broadcast via readlane.
__global__ void __launch_bounds__(256, 2)
gru_kernel(const float* __restrict__ Xf, const float* __restrict__ Mf, const float* __restrict__ Df,
           const float* __restrict__ Xb, const float* __restrict__ Mb, const float* __restrict__ Db,
           const float* __restrict__ wih_f, const float* __restrict__ whh_f,
           const float* __restrict__ bih_f, const float* __restrict__ bhh_f,
           const float* __restrict__ wih_b, const float* __restrict__ whh_b,
           const float* __restrict__ bih_b, const float* __restrict__ bhh_b,
           const float* __restrict__ Wproj,
           float* __restrict__ est_f, float* __restrict__ est_b)
{
  const int lane = threadIdx.x & 63;
  const int wid  = threadIdx.x >> 6;
  const int rho  = blockIdx.x * 4 + wid;        // 0..8191
  const int dir  = rho >> 12;                   // 0 fwd, 1 bwd
  const int n    = rho & (NROW - 1);
  const int b    = n >> 6;
  const int f    = n & 63;

  const float* X   = dir ? Xb    : Xf;
  const float* M   = dir ? Mb    : Mf;
  const float* D   = dir ? Db    : Df;
  const float* wih = dir ? wih_b : wih_f;
  const float* whh = dir ? whh_b : whh_f;
  const float* bih = dir ? bih_b : bih_f;
  const float* bhh = dir ? bhh_b : bhh_f;
  float* est       = dir ? est_b : est_f;

  // per-lane weight rows (unit j = lane)
  float wr[64], wz[64], wn[64];
#pragma unroll
  for (int k = 0; k < 64; k += 4) {
    *(float4*)&wr[k] = *(const float4*)&whh[(0 * H_ + lane) * H_ + k];
    *(float4*)&wz[k] = *(const float4*)&whh[(1 * H_ + lane) * H_ + k];
    *(float4*)&wn[k] = *(const float4*)&whh[(2 * H_ + lane) * H_ + k];
  }
  const float wir0 = wih[(0 * H_ + lane) * 3 + 0];
  const float wir1 = wih[(0 * H_ + lane) * 3 + 1];
  const float wir2 = wih[(0 * H_ + lane) * 3 + 2];
  const float wiz0 = wih[(1 * H_ + lane) * 3 + 0];
  const float wiz1 = wih[(1 * H_ + lane) * 3 + 1];
  const float wiz2 = wih[(1 * H_ + lane) * 3 + 2];
  const float win0 = wih[(2 * H_ + lane) * 3 + 0];
  const float win1 = wih[(2 * H_ + lane) * 3 + 1];
  const float win2 = wih[(2 * H_ + lane) * 3 + 2];
  const float br  = bih[0 * H_ + lane] + bhh[0 * H_ + lane];
  const float bz  = bih[1 * H_ + lane] + bhh[1 * H_ + lane];
  const float bin = bih[2 * H_ + lane];            // kept separate: n = tanh(i_n + r*(gh_n))
  const float bhn = bhh[2 * H_ + lane];
  const float Wp  = Wproj[dir * H_ + lane];

  float h = 0.0f;
  const size_t base = (size_t)b * T_ * F_ + f;
  float xv = X[base], mv = M[base], dv = D[base];

  for (int t = 0; t < T_; ++t) {
    float xn = 0.f, mn = 0.f, dn = 0.f;
    if (t < T_ - 1) {                      // prefetch next step's inputs
      size_t idx = base + (size_t)(t + 1) * F_;
      xn = X[idx]; mn = M[idx]; dn = D[idx];
    }
    float ar = fmaf(xv, wir0, fmaf(mv, wir1, fmaf(dv, wir2, br)));
    float az = fmaf(xv, wiz0, fmaf(mv, wiz1, fmaf(dv, wiz2, bz)));
    float an = fmaf(xv, win0, fmaf(mv, win1, fmaf(dv, win2, bin)));
    float ah = bhn;
#pragma unroll
    for (int k = 0; k < 64; ++k) {
      float hk = bcastf(h, k);
      ar = fmaf(hk, wr[k], ar);
      az = fmaf(hk, wz[k], az);
      ah = fmaf(hk, wn[k], ah);
    }
    float r  = sigm(ar);
    float z  = sigm(az);
    float nn = tanh_f(fmaf(r, ah, an));
    h = fmaf(z, h - nn, nn);               // (1-z)*n + z*h

    float p = h * Wp;                      // est partial; reduce over 64 lanes
#pragma unroll
    for (int off = 32; off; off >>= 1) p += __shfl_xor(p, off, 64);
    if (lane == 0) {
      int tt = dir ? (T_ - 1 - t) : t;     // backward: un-flip
      est[(size_t)tt * NROW + n] = p;
    }
    xv = xn; mv = mn; dv = dn;
  }
}

#define FS 65  /* padded LDS stride: bank = (lane + i) % 32 -> 2 lanes/bank = free */

// One wave per (b,t) sample; lane = output feature o.
__global__ void __launch_bounds__(256, 2)
fcn_kernel(const float* __restrict__ X, const float* __restrict__ M,
           const float* __restrict__ U, const float* __restrict__ V1, const float* __restrict__ V2,
           const float* __restrict__ beta, const float* __restrict__ Wfin, const float* __restrict__ bfin,
           const float* __restrict__ bproj,
           const float* __restrict__ est_f, const float* __restrict__ est_b,
           float* __restrict__ out, float* __restrict__ acc)
{
  __shared__ float sU[64 * FS], sV1[64 * FS], sV2[64 * FS];
  __shared__ float sbeta[64], sbfin[64];
  __shared__ float red[3][4];
  const int tid  = threadIdx.x;
  const int lane = tid & 63;
  const int wid  = tid >> 6;

  for (int idx = tid; idx < 64 * 64; idx += 256) {
    int o = idx >> 6, i = idx & 63;
    sU [o * FS + i] = U [idx];
    sV1[o * FS + i] = V1[idx];
    sV2[o * FS + i] = V2[idx];
  }
  if (tid < 64) { sbeta[tid] = beta[tid]; sbfin[tid] = bfin[tid]; }
  __syncthreads();

  float wfr[64];                           // W_fin row o in VGPRs
#pragma unroll
  for (int k = 0; k < 64; k += 4)
    *(float4*)&wfr[k] = *(const float4*)&Wfin[lane * 64 + k];

  const float bp = bproj[0];
  float se1 = 0.f, se2 = 0.f, sm = 0.f;

  const int SPB = 16;                      // samples per block
  for (int si = 0; si < SPB / 4; ++si) {
    int s  = blockIdx.x * SPB + si * 4 + wid;  // sample id in [0, B*T)
    int bb = s >> 8, t = s & 255;
    size_t gbase = (size_t)s * 64;
    float xr = X[gbase + lane];
    float mr = M[gbase + lane];
    size_t ei = (size_t)t * NROW + (size_t)bb * 64 + lane;
    float re  = est_f[ei] + est_b[ei] + bp;    // RNN_estimation
    float ri  = fmaf(mr, xr - re, re);         // RNN_imputed

    float a1 = sbeta[lane];
#pragma unroll
    for (int i = 0; i < 64; ++i) {
      float xi  = bcastf(xr, i);
      float mi  = bcastf(mr, i);
      float rii = bcastf(ri, i);
      a1 = fmaf(xi,  sU [lane * FS + i], a1);
      a1 = fmaf(rii, sV1[lane * FS + i], a1);
      a1 = fmaf(mi,  sV2[lane * FS + i], a1);
    }
    // remove diagonal contributions (U, V1 have zeroed diagonals)
    a1 -= xr * sU[lane * FS + lane] + ri * sV1[lane * FS + lane];
    float hh = tanh_f(a1);

    float a2 = sbfin[lane];
#pragma unroll
    for (int i = 0; i < 64; ++i)
      a2 = fmaf(bcastf(hh, i), wfr[i], a2);
    float fe = a2;                             // FCN_estimation

    out[gbase + lane] = fmaf(mr, xr - fe, fe); // M*X + (1-M)*FCN_est
    float d1 = (fe - xr) * mr; se1 = fmaf(d1, d1, se1);
    float d2 = (re - xr) * mr; se2 = fmaf(d2, d2, se2);
    sm += mr;
  }

#pragma unroll
  for (int off = 32; off; off >>= 1) {
    se1 += __shfl_xor(se1, off, 64);
    se2 += __shfl_xor(se2, off, 64);
    sm  += __shfl_xor(sm,  off, 64);
  }
  if (lane == 0) { red[0][wid] = se1; red[1][wid] = se2; red[2][wid] = sm; }
  __syncthreads();
  if (tid == 0) {
    atomicAdd(&acc[0], red[0][0] + red[0][1] + red[0][2] + red[0][3]);
    atomicAdd(&acc[1], red[1][0] + red[1][1] + red[1][2] + red[1][3]);
    atomicAdd(&acc[2], red[2][0] + red[2][1] + red[2][2] + red[2][3]);
  }
}

__global__ void loss_kernel(const float* __restrict__ acc, float* __restrict__ out_loss)
{
  if (threadIdx.x == 0 && blockIdx.x == 0) {
    float denom = acc[2] + 1e-12f;
    out_loss[0] = sqrtf(acc[0] / denom) + sqrtf(acc[1] / denom);
  }
}

extern "C" void kernel_launch(void* const* d_in, const int* in_sizes, int n_in,
                              void* d_out, int out_size, void* d_ws, size_t ws_size,
                              hipStream_t stream) {
  const float* Xf    = (const float*)d_in[0];
  const float* Mf    = (const float*)d_in[1];
  const float* Df    = (const float*)d_in[2];
  const float* Xb    = (const float*)d_in[3];
  const float* Mb    = (const float*)d_in[4];
  const float* Db    = (const float*)d_in[5];
  const float* wih_f = (const float*)d_in[6];
  const float* whh_f = (const float*)d_in[7];
  const float* bih_f = (const float*)d_in[8];
  const float* bhh_f = (const float*)d_in[9];
  const float* wih_b = (const float*)d_in[10];
  const float* whh_b = (const float*)d_in[11];
  const float* bih_b = (const float*)d_in[12];
  const float* bhh_b = (const float*)d_in[13];
  const float* Wproj = (const float*)d_in[14];
  const float* bproj = (const float*)d_in[15];
  const float* U     = (const float*)d_in[16];
  const float* V1    = (const float*)d_in[17];
  const float* V2    = (const float*)d_in[18];
  const float* beta  = (const float*)d_in[19];
  const float* Wfin  = (const float*)d_in[20];
  const float* bfin  = (const float*)d_in[21];

  float* est_f = (float*)d_ws;                         // [T, 4096] = 4 MB
  float* est_b = est_f + (size_t)T_ * NROW;            // 4 MB
  float* accp  = est_b + (size_t)T_ * NROW;            // 3 floats

  hipMemsetAsync(accp, 0, 4 * sizeof(float), stream);

  gru_kernel<<<dim3(2048), dim3(256), 0, stream>>>(
      Xf, Mf, Df, Xb, Mb, Db,
      wih_f, whh_f, bih_f, bhh_f,
      wih_b, whh_b, bih_b, bhh_b,
      Wproj, est_f, est_b);

  fcn_kernel<<<dim3(1024), dim3(256), 0, stream>>>(
      Xf, Mf, U, V1, V2, beta, Wfin, bfin, bproj,
      est_f, est_b, (float*)d_out, accp);

  loss_kernel<<<dim3(1), dim3(64), 0, stream>>>(
      accp, (float*)d_out + (size_t)B_ * T_ * F_);
}

// Round 2
// 1508.393 us; speedup vs baseline: 1.0301x; 1.0301x over previous
//
#include <hip/hip_runtime.h>
#include <math.h>

#define B_ 64
#define T_ 256
#define F_ 64
#define H_ 64
#define NROW (B_ * F_) /* 4096 */

__device__ __forceinline__ float bcastf(float v, int k) {
  return __int_as_float(__builtin_amdgcn_readlane(__float_as_int(v), k));
}

__device__ __forceinline__ float sigm(float x) {
  return 1.0f / (1.0f + __expf(-x));
}

__device__ __forceinline__ float tanh_f(float x) {
  float ax = fabsf(x);
  float e = __expf(-2.0f * ax);
  float r = (1.0f - e) / (1.0f + e);
  return copysignf(r, x);
}

// One wave per (direction, row). Lane j owns GRU unit j.
// w_hh rows {j, 64+j, 128+j} live in VGPRs as float4[16] (192 regs, SROA-friendly).
__global__ void __launch_bounds__(256, 2)
gru_kernel(const float* __restrict__ Xf, const float* __restrict__ Mf, const float* __restrict__ Df,
           const float* __restrict__ Xb, const float* __restrict__ Mb, const float* __restrict__ Db,
           const float* __restrict__ wih_f, const float* __restrict__ whh_f,
           const float* __restrict__ bih_f, const float* __restrict__ bhh_f,
           const float* __restrict__ wih_b, const float* __restrict__ whh_b,
           const float* __restrict__ bih_b, const float* __restrict__ bhh_b,
           const float* __restrict__ Wproj,
           float* __restrict__ est_f, float* __restrict__ est_b)
{
  const int lane = threadIdx.x & 63;
  const int wid  = threadIdx.x >> 6;
  const int rho  = blockIdx.x * 4 + wid;        // 0..8191
  const int dir  = rho >> 12;                   // 0 fwd, 1 bwd
  const int n    = rho & (NROW - 1);
  const int b    = n >> 6;
  const int f    = n & 63;

  const float* X   = dir ? Xb    : Xf;
  const float* M   = dir ? Mb    : Mf;
  const float* D   = dir ? Db    : Df;
  const float* wih = dir ? wih_b : wih_f;
  const float* whh = dir ? whh_b : whh_f;
  const float* bih = dir ? bih_b : bih_f;
  const float* bhh = dir ? bhh_b : bhh_f;
  float* est       = dir ? est_b : est_f;

  // per-lane weight rows (unit j = lane), kept as float4 arrays so SROA
  // promotes them to 192 VGPRs (no address-taken float[] alloca).
  float4 wr4[16], wz4[16], wn4[16];
#pragma unroll
  for (int k4 = 0; k4 < 16; ++k4) {
    wr4[k4] = *(const float4*)&whh[(0 * H_ + lane) * H_ + 4 * k4];
    wz4[k4] = *(const float4*)&whh[(1 * H_ + lane) * H_ + 4 * k4];
    wn4[k4] = *(const float4*)&whh[(2 * H_ + lane) * H_ + 4 * k4];
  }
  const float wir0 = wih[(0 * H_ + lane) * 3 + 0];
  const float wir1 = wih[(0 * H_ + lane) * 3 + 1];
  const float wir2 = wih[(0 * H_ + lane) * 3 + 2];
  const float wiz0 = wih[(1 * H_ + lane) * 3 + 0];
  const float wiz1 = wih[(1 * H_ + lane) * 3 + 1];
  const float wiz2 = wih[(1 * H_ + lane) * 3 + 2];
  const float win0 = wih[(2 * H_ + lane) * 3 + 0];
  const float win1 = wih[(2 * H_ + lane) * 3 + 1];
  const float win2 = wih[(2 * H_ + lane) * 3 + 2];
  const float br  = bih[0 * H_ + lane] + bhh[0 * H_ + lane];
  const float bz  = bih[1 * H_ + lane] + bhh[1 * H_ + lane];
  const float bin = bih[2 * H_ + lane];            // n = tanh(i_n + r*gh_n)
  const float bhn = bhh[2 * H_ + lane];
  const float Wp  = Wproj[dir * H_ + lane];

  float h = 0.0f;
  const size_t base = (size_t)b * T_ * F_ + f;
  float xv = X[base], mv = M[base], dv = D[base];

  for (int t = 0; t < T_; ++t) {
    // branchless prefetch of next step's inputs (clamped index)
    size_t nidx = base + (size_t)((t + 1 < T_) ? (t + 1) : t) * F_;
    float xn = X[nidx], mn = M[nidx], dn = D[nidx];

    float ar = fmaf(xv, wir0, fmaf(mv, wir1, fmaf(dv, wir2, br)));
    float az = fmaf(xv, wiz0, fmaf(mv, wiz1, fmaf(dv, wiz2, bz)));
    float an = fmaf(xv, win0, fmaf(mv, win1, fmaf(dv, win2, bin)));
    float ah = bhn;
#pragma unroll
    for (int k4 = 0; k4 < 16; ++k4) {
      const float4 wrv = wr4[k4];
      const float4 wzv = wz4[k4];
      const float4 wnv = wn4[k4];
      float h0 = bcastf(h, 4 * k4 + 0);
      float h1 = bcastf(h, 4 * k4 + 1);
      float h2 = bcastf(h, 4 * k4 + 2);
      float h3 = bcastf(h, 4 * k4 + 3);
      ar = fmaf(h0, wrv.x, ar); az = fmaf(h0, wzv.x, az); ah = fmaf(h0, wnv.x, ah);
      ar = fmaf(h1, wrv.y, ar); az = fmaf(h1, wzv.y, az); ah = fmaf(h1, wnv.y, ah);
      ar = fmaf(h2, wrv.z, ar); az = fmaf(h2, wzv.z, az); ah = fmaf(h2, wnv.z, ah);
      ar = fmaf(h3, wrv.w, ar); az = fmaf(h3, wzv.w, az); ah = fmaf(h3, wnv.w, ah);
    }
    float r  = sigm(ar);
    float z  = sigm(az);
    float nn = tanh_f(fmaf(r, ah, an));
    h = fmaf(z, h - nn, nn);               // (1-z)*n + z*h

    float p = h * Wp;                      // est partial; reduce over 64 lanes
#pragma unroll
    for (int off = 32; off; off >>= 1) p += __shfl_xor(p, off, 64);
    if (lane == 0) {
      int tt = dir ? (T_ - 1 - t) : t;     // backward: un-flip
      est[(size_t)tt * NROW + n] = p;
    }
    xv = xn; mv = mn; dv = dn;
  }
}

#define FS 65  /* padded LDS stride: 2 lanes/bank = free */

// One wave per (b,t) sample; lane = output feature o.
__global__ void __launch_bounds__(256, 2)
fcn_kernel(const float* __restrict__ X, const float* __restrict__ M,
           const float* __restrict__ U, const float* __restrict__ V1, const float* __restrict__ V2,
           const float* __restrict__ beta, const float* __restrict__ Wfin, const float* __restrict__ bfin,
           const float* __restrict__ bproj,
           const float* __restrict__ est_f, const float* __restrict__ est_b,
           float* __restrict__ out, float* __restrict__ acc)
{
  __shared__ float sU[64 * FS], sV1[64 * FS], sV2[64 * FS];
  __shared__ float sbeta[64], sbfin[64];
  __shared__ float red[3][4];
  const int tid  = threadIdx.x;
  const int lane = tid & 63;
  const int wid  = tid >> 6;

  for (int idx = tid; idx < 64 * 64; idx += 256) {
    int o = idx >> 6, i = idx & 63;
    sU [o * FS + i] = U [idx];
    sV1[o * FS + i] = V1[idx];
    sV2[o * FS + i] = V2[idx];
  }
  if (tid < 64) { sbeta[tid] = beta[tid]; sbfin[tid] = bfin[tid]; }
  __syncthreads();

  float4 wfr4[16];                         // W_fin row o in VGPRs
#pragma unroll
  for (int k4 = 0; k4 < 16; ++k4)
    wfr4[k4] = *(const float4*)&Wfin[lane * 64 + 4 * k4];

  const float bp = bproj[0];
  float se1 = 0.f, se2 = 0.f, sm = 0.f;

  const int SPB = 16;                      // samples per block
  for (int si = 0; si < SPB / 4; ++si) {
    int s  = blockIdx.x * SPB + si * 4 + wid;  // sample id in [0, B*T)
    int bb = s >> 8, t = s & 255;
    size_t gbase = (size_t)s * 64;
    float xr = X[gbase + lane];
    float mr = M[gbase + lane];
    size_t ei = (size_t)t * NROW + (size_t)bb * 64 + lane;
    float re  = est_f[ei] + est_b[ei] + bp;    // RNN_estimation
    float ri  = fmaf(mr, xr - re, re);         // RNN_imputed

    float a1 = sbeta[lane];
#pragma unroll
    for (int i = 0; i < 64; ++i) {
      float xi  = bcastf(xr, i);
      float mi  = bcastf(mr, i);
      float rii = bcastf(ri, i);
      a1 = fmaf(xi,  sU [lane * FS + i], a1);
      a1 = fmaf(rii, sV1[lane * FS + i], a1);
      a1 = fmaf(mi,  sV2[lane * FS + i], a1);
    }
    // remove diagonal contributions (U, V1 have zeroed diagonals)
    a1 -= xr * sU[lane * FS + lane] + ri * sV1[lane * FS + lane];
    float hh = tanh_f(a1);

    float a2 = sbfin[lane];
#pragma unroll
    for (int k4 = 0; k4 < 16; ++k4) {
      const float4 w = wfr4[k4];
      a2 = fmaf(bcastf(hh, 4 * k4 + 0), w.x, a2);
      a2 = fmaf(bcastf(hh, 4 * k4 + 1), w.y, a2);
      a2 = fmaf(bcastf(hh, 4 * k4 + 2), w.z, a2);
      a2 = fmaf(bcastf(hh, 4 * k4 + 3), w.w, a2);
    }
    float fe = a2;                             // FCN_estimation

    out[gbase + lane] = fmaf(mr, xr - fe, fe); // M*X + (1-M)*FCN_est
    float d1 = (fe - xr) * mr; se1 = fmaf(d1, d1, se1);
    float d2 = (re - xr) * mr; se2 = fmaf(d2, d2, se2);
    sm += mr;
  }

#pragma unroll
  for (int off = 32; off; off >>= 1) {
    se1 += __shfl_xor(se1, off, 64);
    se2 += __shfl_xor(se2, off, 64);
    sm  += __shfl_xor(sm,  off, 64);
  }
  if (lane == 0) { red[0][wid] = se1; red[1][wid] = se2; red[2][wid] = sm; }
  __syncthreads();
  if (tid == 0) {
    atomicAdd(&acc[0], red[0][0] + red[0][1] + red[0][2] + red[0][3]);
    atomicAdd(&acc[1], red[1][0] + red[1][1] + red[1][2] + red[1][3]);
    atomicAdd(&acc[2], red[2][0] + red[2][1] + red[2][2] + red[2][3]);
  }
}

__global__ void loss_kernel(const float* __restrict__ acc, float* __restrict__ out_loss)
{
  if (threadIdx.x == 0 && blockIdx.x == 0) {
    float denom = acc[2] + 1e-12f;
    out_loss[0] = sqrtf(acc[0] / denom) + sqrtf(acc[1] / denom);
  }
}

extern "C" void kernel_launch(void* const* d_in, const int* in_sizes, int n_in,
                              void* d_out, int out_size, void* d_ws, size_t ws_size,
                              hipStream_t stream) {
  const float* Xf    = (const float*)d_in[0];
  const float* Mf    = (const float*)d_in[1];
  const float* Df    = (const float*)d_in[2];
  const float* Xb    = (const float*)d_in[3];
  const float* Mb    = (const float*)d_in[4];
  const float* Db    = (const float*)d_in[5];
  const float* wih_f = (const float*)d_in[6];
  const float* whh_f = (const float*)d_in[7];
  const float* bih_f = (const float*)d_in[8];
  const float* bhh_f = (const float*)d_in[9];
  const float* wih_b = (const float*)d_in[10];
  const float* whh_b = (const float*)d_in[11];
  const float* bih_b = (const float*)d_in[12];
  const float* bhh_b = (const float*)d_in[13];
  const float* Wproj = (const float*)d_in[14];
  const float* bproj = (const float*)d_in[15];
  const float* U     = (const float*)d_in[16];
  const float* V1    = (const float*)d_in[17];
  const float* V2    = (const float*)d_in[18];
  const float* beta  = (const float*)d_in[19];
  const float* Wfin  = (const float*)d_in[20];
  const float* bfin  = (const float*)d_in[21];

  float* est_f = (float*)d_ws;                         // [T, 4096] = 4 MB
  float* est_b = est_f + (size_t)T_ * NROW;            // 4 MB
  float* accp  = est_b + (size_t)T_ * NROW;            // 3 floats

  hipMemsetAsync(accp, 0, 4 * sizeof(float), stream);

  gru_kernel<<<dim3(2048), dim3(256), 0, stream>>>(
      Xf, Mf, Df, Xb, Mb, Db,
      wih_f, whh_f, bih_f, bhh_f,
      wih_b, whh_b, bih_b, bhh_b,
      Wproj, est_f, est_b);

  fcn_kernel<<<dim3(1024), dim3(256), 0, stream>>>(
      Xf, Mf, U, V1, V2, beta, Wfin, bfin, bproj,
      est_f, est_b, (float*)d_out, accp);

  loss_kernel<<<dim3(1), dim3(64), 0, stream>>>(
      accp, (float*)d_out + (size_t)B_ * T_ * F_);
}